// Round 4
// baseline (2923.012 us; speedup 1.0000x reference)
//
#include <hip/hip_runtime.h>

// Problem constants
#define BSZ  128
#define TT   50
#define CIN  2312
#define HID  300
#define NOUT 10
#define KS   5
#define T1   51          // (TT+5) - KS + 1
#define T2   52          // (T1+5) - KS + 1
#define BKc  8           // i-chunk width (CIN = 8 * 289 exactly)

typedef unsigned int u32;

// ---------------------------------------------------------------------------
// Layer-1 tile: fp64 GEMM (64 t-rows x 64 o-cols x CIN*KS) for NB batches,
// gauss kernel synthesized in double on the fly, then in-LDS fp64 LIF scan,
// ballot bit-pack of spikes.
// dsm: >= 5120 doubles (NB=2) / >= 4096 doubles (NB=1).
// Layout: Bs double[KS][BKc][64] at dsm[0,2560); As float[NB][KS][BKc][64]
// at dsm+2560. y1s double[64][64] overlays dsm[0,4096) after the GEMM.
// ---------------------------------------------------------------------------
template<int NB>
__device__ __forceinline__ void layer1_tile(
    int b0, int b1, int ow, int tid,
    const float* __restrict__ data, const float* __restrict__ W1,
    const float* __restrict__ P1, const float* __restrict__ b1v,
    double* __restrict__ dsm, u32* __restrict__ bits0, u32* __restrict__ bits1)
{
  double (*Bs)[BKc][64] = (double(*)[BKc][64])dsm;
  float* Af = (float*)(dsm + KS * BKc * 64);          // NB*2560 floats

  const int row = tid & 63;            // t-row (A) / o-row (B)
  const int sub = tid >> 6;            // 0..3

  const int bo = ow * 64 + row;
  const bool ovalid = bo < HID;
  const float* wrow = W1 + (size_t)(ovalid ? bo : 0) * CIN;
  const float* prow = P1 + (size_t)(ovalid ? bo : 0) * CIN;

  const int ty = tid >> 4;             // 0..15 -> t rows 4ty..+3
  const int tx = tid & 15;             // 0..15 -> o cols 4tx..+3

  double acc[NB][4][4];
#pragma unroll
  for (int n = 0; n < NB; ++n)
#pragma unroll
    for (int r = 0; r < 4; ++r)
#pragma unroll
      for (int c = 0; c < 4; ++c) acc[n][r][c] = 0.0;

  const int anb   = (NB == 2) ? (sub >> 1) : 0;      // which batch this thread stages
  const int ihalf = sub & 1;                          // 4-float half of the 8-chunk
  const int bsel  = (NB == 2) ? ((anb == 0) ? b0 : b1) : b0;
  const float* abase = data + (size_t)bsel * (TT * CIN);

  for (int i0 = 0; i0 < CIN; i0 += BKc) {            // 289 chunks, no remainder
    // ---- stage A: 5 time-shifted taps, fp32 exact ----
#pragma unroll
    for (int k = 0; k < KS; ++k) {
      const int tp = row + k - KS;                   // t + k - 5; <= 49 when row<T1
      float4 v;
      if (row < T1 && tp >= 0)
        v = *(const float4*)(abase + (size_t)tp * CIN + i0 + ihalf * 4);
      else
        v = make_float4(0.f, 0.f, 0.f, 0.f);
      float* dst = Af + ((anb * KS + k) * BKc + ihalf * 4) * 64 + row;
      dst[0 * 64] = v.x; dst[1 * 64] = v.y; dst[2 * 64] = v.z; dst[3 * 64] = v.w;
    }
    // ---- stage B: synthesize gauss taps in double ----
    {
      float2 wv = make_float2(0.f, 0.f), pv = make_float2(0.f, 0.f);
      if (ovalid) {
        wv = *(const float2*)(wrow + i0 + sub * 2);
        pv = *(const float2*)(prow + i0 + sub * 2);
      }
#pragma unroll
      for (int j = 0; j < 2; ++j) {
        const double w = (j == 0) ? (double)wv.x : (double)wv.y;
        const double p = (j == 0) ? (double)pv.x : (double)pv.y;
        const double c = p + 2.0;                    // P + MAX_DELAY//2
        // e_k = exp(-(k-c)^2/8) = E0 * U^k * exp(-k^2/8)
        const double E0 = ::exp(c * c * (-0.125));
        const double U  = ::exp(c * 0.25);
        const double u2 = U * U;
        const double e0 = E0;
        const double e1 = E0 * U  * 0.88249690258459546;   // exp(-1/8)
        const double e2 = E0 * u2 * 0.60653065971263342;   // exp(-1/2)
        const double e3 = E0 * (u2 * U) * 0.32465246735834974;   // exp(-9/8)
        const double e4 = E0 * (u2 * u2) * 0.13533528323661270;  // exp(-2)
        const double s  = ((((e0 + e1) + e2) + e3) + e4) + 1e-7;
        const double inv = 1.0 / s;
        const int col = sub * 2 + j;
        Bs[0][col][row] = w * (e0 * inv);
        Bs[1][col][row] = w * (e1 * inv);
        Bs[2][col][row] = w * (e2 * inv);
        Bs[3][col][row] = w * (e3 * inv);
        Bs[4][col][row] = w * (e4 * inv);
      }
    }
    __syncthreads();

    // ---- fp64 FMA micro-kernel: 5 taps x 8 k-steps x NB x 4x4 ----
    for (int k = 0; k < KS; ++k) {
#pragma unroll
      for (int kk = 0; kk < BKc; ++kk) {
        const double* bp = &Bs[k][kk][tx << 2];
        const double q0 = bp[0], q1 = bp[1], q2 = bp[2], q3 = bp[3];
#pragma unroll
        for (int n = 0; n < NB; ++n) {
          const float* ap = Af + ((n * KS + k) * BKc + kk) * 64 + (ty << 2);
          const float4 av = *(const float4*)ap;
          const double a0 = (double)av.x, a1 = (double)av.y;
          const double a2 = (double)av.z, a3 = (double)av.w;
          acc[n][0][0] = fma(a0, q0, acc[n][0][0]);
          acc[n][0][1] = fma(a0, q1, acc[n][0][1]);
          acc[n][0][2] = fma(a0, q2, acc[n][0][2]);
          acc[n][0][3] = fma(a0, q3, acc[n][0][3]);
          acc[n][1][0] = fma(a1, q0, acc[n][1][0]);
          acc[n][1][1] = fma(a1, q1, acc[n][1][1]);
          acc[n][1][2] = fma(a1, q2, acc[n][1][2]);
          acc[n][1][3] = fma(a1, q3, acc[n][1][3]);
          acc[n][2][0] = fma(a2, q0, acc[n][2][0]);
          acc[n][2][1] = fma(a2, q1, acc[n][2][1]);
          acc[n][2][2] = fma(a2, q2, acc[n][2][2]);
          acc[n][2][3] = fma(a2, q3, acc[n][2][3]);
          acc[n][3][0] = fma(a3, q0, acc[n][3][0]);
          acc[n][3][1] = fma(a3, q1, acc[n][3][1]);
          acc[n][3][2] = fma(a3, q2, acc[n][3][2]);
          acc[n][3][3] = fma(a3, q3, acc[n][3][3]);
        }
      }
    }
    __syncthreads();
  }

  // ---- per-batch: y1 tile -> LDS (double), fp64 LIF scan, ballot pack ----
  double (*y1s)[64] = (double(*)[64])dsm;            // 64x64 doubles, overlays Bs/As
#pragma unroll
  for (int n = 0; n < NB; ++n) {
#pragma unroll
    for (int r = 0; r < 4; ++r) {
      const int t = (ty << 2) + r;
#pragma unroll
      for (int c = 0; c < 4; ++c) y1s[t][(tx << 2) + c] = acc[n][r][c];
    }
    __syncthreads();
    if (tid < 64) {                                  // wave 0
      const int o = ow * 64 + tid;
      const bool valid = o < HID;
      const double bias = valid ? (double)b1v[o] : 0.0;
      u32* bptr = (n == 0) ? bits0 : bits1;
      double mem = 0.0;
      for (int t = 0; t < T1; ++t) {
        const double x = y1s[t][tid] + bias;
        const double reset = (mem > 1.0) ? 1.0 : 0.0;
        mem = __dsub_rn(__dadd_rn(__dmul_rn(0.9, mem), x), reset);
        const unsigned long long mk = __ballot(valid && (mem > 1.0));
        if (tid == 0)  bptr[t * 10 + 2 * ow]     = (u32)mk;
        if (tid == 32) bptr[t * 10 + 2 * ow + 1] = (u32)(mk >> 32);
      }
    }
    __syncthreads();
  }
}

// ---------------------------------------------------------------------------
// Layer-2 conv + LIF2 (fp32), spike bits already in LDS at smem+15000.
// smem floats: [0,15000) K2s [o][k][i], [15000,15510) lbits u32,
// [15510,16030) y2s [t2][o].
// ---------------------------------------------------------------------------
__device__ __forceinline__ void layer2_lif2(
    int b, int tid, float* smem,
    const float* __restrict__ W2, const float* __restrict__ P2,
    const float* __restrict__ b2, float* __restrict__ out)
{
  float* K2s = smem;
  const u32* lbits = (const u32*)(smem + 15000);
  float* y2s = smem + 15510;

  for (int idx = tid; idx < NOUT * HID; idx += 256) {
    const int o = idx / HID, i = idx % HID;
    const float w = W2[idx], p = P2[idx];
    const float c = p + 2.0f;
    float e[KS], s = 0.f;
#pragma unroll
    for (int k = 0; k < KS; ++k) {
      const float d = ((float)k - c) * 0.5f;
      e[k] = __expf(-0.5f * d * d);
      s += e[k];
    }
    const float denom = s + 1e-7f;
#pragma unroll
    for (int k = 0; k < KS; ++k)
      K2s[(o * KS + k) * HID + i] = w * (e[k] / denom);
  }
  __syncthreads();                    // also fences lbits population

  for (int task = tid; task < T2 * NOUT; task += 256) {
    const int t2 = task / NOUT, o = task % NOUT;
    float acc = b2[o];
#pragma unroll
    for (int k = 0; k < KS; ++k) {
      const int tp = t2 + k - KS;
      if (tp < 0 || tp >= T1) continue;
      const float* kr = K2s + (o * KS + k) * HID;
      const u32* br = lbits + tp * 10;
      for (int i = 0; i < HID; ++i)
        acc = fmaf((float)((br[i >> 5] >> (i & 31)) & 1u), kr[i], acc);
    }
    y2s[task] = acc;
  }
  __syncthreads();

  if (tid < NOUT) {
    float mem = 0.f;
    for (int t = 0; t < T2; ++t) {
      const float x = y2s[t * NOUT + tid];
      const float reset = (mem > 1.0f) ? 1.0f : 0.0f;
      mem = __fsub_rn(__fadd_rn(__fmul_rn(0.9f, mem), x), reset);
      out[(size_t)t * (BSZ * NOUT) + b * NOUT + tid] = (mem > 1.0f) ? 1.0f : 0.0f;
      out[(size_t)T2 * BSZ * NOUT + (size_t)t * (BSZ * NOUT) + b * NOUT + tid] = mem;
    }
  }
}

// ---------------- split path ------------------------------------------------
__global__ __launch_bounds__(256) void snn_l1(
    const float* __restrict__ data, const float* __restrict__ W1,
    const float* __restrict__ P1, const float* __restrict__ b1v,
    u32* __restrict__ gbits)
{
  __shared__ double dsm[5120];       // 40 KiB
  const int ow = blockIdx.x, pb = blockIdx.y;
  layer1_tile<2>(pb, pb + 64, ow, threadIdx.x, data, W1, P1, b1v, dsm,
                 gbits + (size_t)pb * 510, gbits + (size_t)(pb + 64) * 510);
}

__global__ __launch_bounds__(256) void snn_l2k(
    const u32* __restrict__ gbits,
    const float* __restrict__ W2, const float* __restrict__ P2,
    const float* __restrict__ b2, float* __restrict__ out)
{
  __shared__ float smem[16030];      // 64120 B
  const int b = blockIdx.x, tid = threadIdx.x;
  u32* lbits = (u32*)(smem + 15000);
  for (int i = tid; i < 510; i += 256) lbits[i] = gbits[(size_t)b * 510 + i];
  layer2_lif2(b, tid, smem, W2, P2, b2, out);
}

// ---------------- zero-workspace fallback -----------------------------------
__global__ __launch_bounds__(256) void snn_mono(
    const float* __restrict__ data, const float* __restrict__ W1,
    const float* __restrict__ P1, const float* __restrict__ b1v,
    const float* __restrict__ W2, const float* __restrict__ P2,
    const float* __restrict__ b2, float* __restrict__ out)
{
  __shared__ double dsm[8015];       // 64120 B
  const int b = blockIdx.x, tid = threadIdx.x;
  u32* lbits = (u32*)((float*)dsm + 15000);
  for (int ow = 0; ow < 5; ++ow)
    layer1_tile<1>(b, b, ow, tid, data, W1, P1, b1v, dsm, lbits, lbits);
  layer2_lif2(b, tid, (float*)dsm, W2, P2, b2, out);
}

// ---------------- launcher --------------------------------------------------
extern "C" void kernel_launch(void* const* d_in, const int* in_sizes, int n_in,
                              void* d_out, int out_size, void* d_ws, size_t ws_size,
                              hipStream_t stream) {
  const float* data = (const float*)d_in[0];
  const float* W1   = (const float*)d_in[1];
  const float* P1   = (const float*)d_in[2];
  const float* b1v  = (const float*)d_in[3];
  const float* W2   = (const float*)d_in[4];
  const float* P2   = (const float*)d_in[5];
  const float* b2   = (const float*)d_in[6];
  float* out = (float*)d_out;

  const size_t BITS_BYTES = (size_t)BSZ * T1 * 10 * sizeof(u32);  // 261,120 B

  if (ws_size >= BITS_BYTES) {
    u32* gbits = (u32*)d_ws;
    snn_l1<<<dim3(5, 64), 256, 0, stream>>>(data, W1, P1, b1v, gbits);
    snn_l2k<<<BSZ, 256, 0, stream>>>(gbits, W2, P2, b2, out);
  } else {
    snn_mono<<<BSZ, 256, 0, stream>>>(data, W1, P1, b1v, W2, P2, b2, out);
  }
}

// Round 5
// 2157.064 us; speedup vs baseline: 1.3551x; 1.3551x over previous
//
#include <hip/hip_runtime.h>

// Problem constants
#define BSZ  128
#define TT   50
#define CIN  2312
#define HID  300
#define NOUT 10
#define KS   5
#define T1   51          // (TT+5) - KS + 1
#define T2   52          // (T1+5) - KS + 1

typedef unsigned int u32;

// exp(-k^2/8) constants, k=1..4
#define EK1 0.88249690258459546
#define EK2 0.60653065971263342
#define EK3 0.32465246735834974
#define EK4 0.13533528323661270

// ---------------------------------------------------------------------------
// Layer-1 tile for (batch b, o-tile ow): fp64 GEMM 64t(51 valid) x 64o over
// K = CIN*KS. A staged ONCE as a 55-slot time window shared by all 5 taps
// (slot = t + k, tp = slot - 5). Gauss weights synthesized in fp64 on the fly.
// Then in-LDS fp64 LIF scan + ballot bit-pack.
// dsm >= 3264 doubles. Layout: Bs double[5][8][64] at [0,2560);
// As float[8][80] at doubles [2560,2880); y1s double[51][64] overlays [0,3264).
// ---------------------------------------------------------------------------
__device__ __forceinline__ void layer1_tile(
    int b, int ow, int tid,
    const float* __restrict__ data, const float* __restrict__ W1,
    const float* __restrict__ P1, const float* __restrict__ b1v,
    double* __restrict__ dsm, u32* __restrict__ bits)
{
  double (*Bs)[8][64] = (double(*)[8][64])dsm;     // [k][isub][o]
  float* As = (float*)(dsm + 2560);                // [kk][80] slots

  const int ty = tid >> 5;                         // 0..7  -> rows 8ty..+7
  const int tx = tid & 31;                         // 0..31 -> cols 2tx..+1
  const int r0 = ty << 3;
  const int c0 = tx << 1;

  const float* abase = data + (size_t)b * (TT * CIN);
  const int bo_stage = ow * 64 + ((tid >> 3) & 63);

  double acc[8][2];
#pragma unroll
  for (int r = 0; r < 8; ++r) { acc[r][0] = 0.0; acc[r][1] = 0.0; }

  for (int i0 = 0; i0 < CIN; i0 += 8) {            // 289 chunks exactly
    // ---- stage A: one 55-slot time window, fp32 (220 threads) ----
    if (tid < 220) {
      const int slot = tid >> 2;                   // 0..54
      const int pair = tid & 3;                    // 0..3 -> i-subs 2p,2p+1
      const int tp = slot - 5;                     // -5..49 (< TT always)
      float2 v;
      if (tp >= 0) v = *(const float2*)(abase + (size_t)tp * CIN + i0 + 2 * pair);
      else         v = make_float2(0.f, 0.f);
      As[(2 * pair) * 80 + slot]     = v.x;
      As[(2 * pair + 1) * 80 + slot] = v.y;
    }
    // ---- stage B: synthesize 5 gauss taps in fp64 (512 cells, 2/thread) ----
    for (int u = tid; u < 512; u += 256) {
      const int o = u >> 3, isub = u & 7;
      const int bo = ow * 64 + o;
      double w = 0.0, p = 0.0;
      if (bo < HID) {
        const size_t gi = (size_t)bo * CIN + i0 + isub;
        w = (double)W1[gi];
        p = (double)P1[gi];
      }
      const double c = p + 2.0;                    // P + MAX_DELAY//2
      // e_k = exp(-(k-c)^2/8) = E0 * U^k * exp(-k^2/8)
      const double E0 = ::exp(c * c * (-0.125));
      const double U  = ::exp(c * 0.25);
      const double u2 = U * U;
      const double e0 = E0;
      const double e1 = E0 * U * EK1;
      const double e2 = E0 * u2 * EK2;
      const double e3 = E0 * (u2 * U) * EK3;
      const double e4 = E0 * (u2 * u2) * EK4;
      const double inv = 1.0 / (((((e0 + e1) + e2) + e3) + e4) + 1e-7);
      Bs[0][isub][o] = w * (e0 * inv);
      Bs[1][isub][o] = w * (e1 * inv);
      Bs[2][isub][o] = w * (e2 * inv);
      Bs[3][isub][o] = w * (e3 * inv);
      Bs[4][isub][o] = w * (e4 * inv);
    }
    __syncthreads();

    // ---- compute: 8 i-steps x 5 taps x (8x2) micro-tile ----
#pragma unroll
    for (int kk = 0; kk < 8; ++kk) {
      const float* ap = &As[kk * 80 + r0];         // slots r0..r0+11 (aligned)
      const float4 a0 = *(const float4*)(ap);
      const float4 a1 = *(const float4*)(ap + 4);
      const float4 a2 = *(const float4*)(ap + 8);
      double av[12];
      av[0] = a0.x; av[1] = a0.y; av[2]  = a0.z; av[3]  = a0.w;
      av[4] = a1.x; av[5] = a1.y; av[6]  = a1.z; av[7]  = a1.w;
      av[8] = a2.x; av[9] = a2.y; av[10] = a2.z; av[11] = a2.w;
      double bv[KS][2];
#pragma unroll
      for (int k = 0; k < KS; ++k) {
        const double2 bb = *(const double2*)&Bs[k][kk][c0];
        bv[k][0] = bb.x; bv[k][1] = bb.y;
      }
#pragma unroll
      for (int k = 0; k < KS; ++k)
#pragma unroll
        for (int r = 0; r < 8; ++r) {
          acc[r][0] = fma(av[r + k], bv[k][0], acc[r][0]);
          acc[r][1] = fma(av[r + k], bv[k][1], acc[r][1]);
        }
    }
    __syncthreads();
  }

  // ---- y1 tile -> LDS (overlays Bs/As; fenced by loop-final sync) ----
  double* y1s = dsm;                               // [t][64], t<51
#pragma unroll
  for (int r = 0; r < 8; ++r) {
    const int t = r0 + r;
    if (t < T1) {
      y1s[t * 64 + c0]     = acc[r][0];
      y1s[t * 64 + c0 + 1] = acc[r][1];
    }
  }
  __syncthreads();

  // ---- fp64 LIF scan on wave 0 + ballot bit-pack ----
  if (tid < 64) {
    const int o = ow * 64 + tid;
    const bool valid = o < HID;
    const double bias = valid ? (double)b1v[o] : 0.0;
    double mem = 0.0;
    for (int t = 0; t < T1; ++t) {
      const double x = y1s[t * 64 + tid] + bias;
      const double reset = (mem > 1.0) ? 1.0 : 0.0;
      mem = __dsub_rn(__dadd_rn(__dmul_rn(0.9, mem), x), reset);
      const unsigned long long mk = __ballot(valid && (mem > 1.0));
      if (tid == 0)  bits[t * 10 + 2 * ow]     = (u32)mk;
      if (tid == 32) bits[t * 10 + 2 * ow + 1] = (u32)(mk >> 32);
    }
  }
  __syncthreads();
  (void)bo_stage;
}

// ---------------------------------------------------------------------------
// Layer-2 conv + LIF2 (fp32), spike bits already in LDS at smem+15000.
// smem floats: [0,15000) K2s [o][k][i], [15000,15510) lbits u32,
// [15510,16030) y2s [t2][o].
// ---------------------------------------------------------------------------
__device__ __forceinline__ void layer2_lif2(
    int b, int tid, float* smem,
    const float* __restrict__ W2, const float* __restrict__ P2,
    const float* __restrict__ b2, float* __restrict__ out)
{
  float* K2s = smem;
  const u32* lbits = (const u32*)(smem + 15000);
  float* y2s = smem + 15510;

  for (int idx = tid; idx < NOUT * HID; idx += 256) {
    const int o = idx / HID, i = idx % HID;
    const float w = W2[idx], p = P2[idx];
    const float c = p + 2.0f;
    float e[KS], s = 0.f;
#pragma unroll
    for (int k = 0; k < KS; ++k) {
      const float d = ((float)k - c) * 0.5f;
      e[k] = __expf(-0.5f * d * d);
      s += e[k];
    }
    const float denom = s + 1e-7f;
#pragma unroll
    for (int k = 0; k < KS; ++k)
      K2s[(o * KS + k) * HID + i] = w * (e[k] / denom);
  }
  __syncthreads();                    // also fences lbits population

  for (int task = tid; task < T2 * NOUT; task += 256) {
    const int t2 = task / NOUT, o = task % NOUT;
    float acc = b2[o];
#pragma unroll
    for (int k = 0; k < KS; ++k) {
      const int tp = t2 + k - KS;
      if (tp < 0 || tp >= T1) continue;
      const float* kr = K2s + (o * KS + k) * HID;
      const u32* br = lbits + tp * 10;
      for (int i = 0; i < HID; ++i)
        acc = fmaf((float)((br[i >> 5] >> (i & 31)) & 1u), kr[i], acc);
    }
    y2s[task] = acc;
  }
  __syncthreads();

  if (tid < NOUT) {
    float mem = 0.f;
    for (int t = 0; t < T2; ++t) {
      const float x = y2s[t * NOUT + tid];
      const float reset = (mem > 1.0f) ? 1.0f : 0.0f;
      mem = __fsub_rn(__fadd_rn(__fmul_rn(0.9f, mem), x), reset);
      out[(size_t)t * (BSZ * NOUT) + b * NOUT + tid] = (mem > 1.0f) ? 1.0f : 0.0f;
      out[(size_t)T2 * BSZ * NOUT + (size_t)t * (BSZ * NOUT) + b * NOUT + tid] = mem;
    }
  }
}

// ---------------- split path ------------------------------------------------
__global__ __launch_bounds__(256) void snn_l1(
    const float* __restrict__ data, const float* __restrict__ W1,
    const float* __restrict__ P1, const float* __restrict__ b1v,
    u32* __restrict__ gbits)
{
  __shared__ double dsm[3264];       // 26112 B
  const int ow = blockIdx.x, b = blockIdx.y;
  layer1_tile(b, ow, threadIdx.x, data, W1, P1, b1v, dsm,
              gbits + (size_t)b * 510);
}

__global__ __launch_bounds__(256) void snn_l2k(
    const u32* __restrict__ gbits,
    const float* __restrict__ W2, const float* __restrict__ P2,
    const float* __restrict__ b2, float* __restrict__ out)
{
  __shared__ float smem[16030];      // 64120 B
  const int b = blockIdx.x, tid = threadIdx.x;
  u32* lbits = (u32*)(smem + 15000);
  for (int i = tid; i < 510; i += 256) lbits[i] = gbits[(size_t)b * 510 + i];
  layer2_lif2(b, tid, smem, W2, P2, b2, out);
}

// ---------------- zero-workspace fallback -----------------------------------
__global__ __launch_bounds__(256) void snn_mono(
    const float* __restrict__ data, const float* __restrict__ W1,
    const float* __restrict__ P1, const float* __restrict__ b1v,
    const float* __restrict__ W2, const float* __restrict__ P2,
    const float* __restrict__ b2, float* __restrict__ out)
{
  __shared__ double dsm[8015];       // 64120 B; layer1 uses [0,3264)
  const int b = blockIdx.x, tid = threadIdx.x;
  u32* lbits = (u32*)((float*)dsm + 15000);   // float-offset 15000 = byte 60000
  for (int ow = 0; ow < 5; ++ow)
    layer1_tile(b, ow, tid, data, W1, P1, b1v, dsm, lbits);
  layer2_lif2(b, tid, (float*)dsm, W2, P2, b2, out);
}

// ---------------- launcher --------------------------------------------------
extern "C" void kernel_launch(void* const* d_in, const int* in_sizes, int n_in,
                              void* d_out, int out_size, void* d_ws, size_t ws_size,
                              hipStream_t stream) {
  const float* data = (const float*)d_in[0];
  const float* W1   = (const float*)d_in[1];
  const float* P1   = (const float*)d_in[2];
  const float* b1v  = (const float*)d_in[3];
  const float* W2   = (const float*)d_in[4];
  const float* P2   = (const float*)d_in[5];
  const float* b2   = (const float*)d_in[6];
  float* out = (float*)d_out;

  const size_t BITS_BYTES = (size_t)BSZ * T1 * 10 * sizeof(u32);  // 261,120 B

  if (ws_size >= BITS_BYTES) {
    u32* gbits = (u32*)d_ws;
    snn_l1<<<dim3(5, BSZ), 256, 0, stream>>>(data, W1, P1, b1v, gbits);
    snn_l2k<<<BSZ, 256, 0, stream>>>(gbits, W2, P2, b2, out);
  } else {
    snn_mono<<<BSZ, 256, 0, stream>>>(data, W1, P1, b1v, W2, P2, b2, out);
  }
}